// Round 4
// baseline (805.137 us; speedup 1.0000x reference)
//
#include <hip/hip_runtime.h>
#include <cmath>

#define GXN 240
#define GYN 121
#define SP  29040   // GXN*GYN
#define NB  8
#define NCH 213
#define EPSV 1e-6f
#define DMAXF 7.75f   // sqrt(2*30) * ls  -> weight >= ~9.4e-14 kept
#define ACLIP -30.0f

// unified off-grid point space: HadISD(32 vb x 5000) + ICOADS(8 x 20000) + IGRA(8 x 3000)
#define P_HAD   160000
#define P_ICO   160000
#define P_IGRA  24000
#define PT_TOT  344000
#define VB_TOT  48
#define NCELL   (VB_TOT*SP)   // 1,393,920
#define CBLK    908           // ceil(NB*SP/256)
#define NGROUP  39

__device__ __forceinline__ float gxv(int i){ return (float)i * (1.0f/239.0f); }
__device__ __forceinline__ float gyv(int j){ return -0.25f + (float)j * (1.0f/240.0f); }
__device__ __forceinline__ size_t oidx(int b,int c,int i,int j){
  return (((size_t)b*NCH + c)*GXN + i)*GYN + j;
}
__device__ __forceinline__ int binx(float x){
  int i = (int)floorf(x*239.0f + 0.5f);
  return i<0?0:(i>239?239:i);
}
__device__ __forceinline__ int biny(float y){
  int j = (int)floorf((y+0.25f)*240.0f + 0.5f);
  return j<0?0:(j>120?120:j);
}
__device__ __forceinline__ int lbnd(const float* a, int n, float v){
  int lo=0, hi=n;
  while(lo<hi){ int m=(lo+hi)>>1; if(a[m]<v) lo=m+1; else hi=m; }
  return lo;
}
__device__ __forceinline__ int ubnd(const float* a, int n, float v){
  int lo=0, hi=n;
  while(lo<hi){ int m=(lo+hi)>>1; if(a[m]<=v) lo=m+1; else hi=m; }
  return lo;
}

// map unified point idx -> (dataset, vb, n, x, y)
struct PtLoc { int ds, vb, n; float x, y; };
__device__ __forceinline__ PtLoc ptloc(int idx, const float* hadx, const float* icx, const float* igx){
  PtLoc p;
  if(idx < P_HAD){
    p.ds=0; p.vb=idx/5000; p.n=idx%5000;
    p.x = hadx[(size_t)p.vb*10000 + p.n];
    p.y = hadx[(size_t)p.vb*10000 + 5000 + p.n];
  } else if(idx < P_HAD + P_ICO){
    int t = idx - P_HAD; p.ds=1; p.vb=t/20000; p.n=t%20000;
    p.x = icx[(size_t)p.vb*40000 + p.n];
    p.y = icx[(size_t)p.vb*40000 + 20000 + p.n];
  } else {
    int t = idx - (P_HAD+P_ICO); p.ds=2; p.vb=t/3000; p.n=t%3000;
    p.x = igx[(size_t)p.vb*6000 + p.n];
    p.y = igx[(size_t)p.vb*6000 + 3000 + p.n];
  }
  return p;
}
__device__ __forceinline__ int vbglobal(const PtLoc& p){
  return (p.ds==0)? p.vb : (p.ds==1? 32+p.vb : 40+p.vb);
}

// ====================== binning pipeline ====================================
__global__ void kzero_i(int* __restrict__ p, int n){
  int i = blockIdx.x*blockDim.x + threadIdx.x;
  if(i<n) p[i]=0;
}

__global__ void kcount(const float* __restrict__ hadx, const float* __restrict__ icx,
                       const float* __restrict__ igx, int* __restrict__ counts){
  int idx = blockIdx.x*blockDim.x + threadIdx.x;
  if(idx >= PT_TOT) return;
  PtLoc p = ptloc(idx, hadx, icx, igx);
  atomicAdd(counts + vbglobal(p)*SP + binx(p.x)*GYN + biny(p.y), 1);
}

__global__ void kscan1(const int* __restrict__ in, int* __restrict__ part,
                       int* __restrict__ bsum, int n){
  __shared__ int ts[256];
  int t = threadIdx.x;
  int base = blockIdx.x*1024 + t*4;
  int v0=0,v1=0,v2=0,v3=0;
  if(base+0<n) v0=in[base+0];
  if(base+1<n) v1=in[base+1];
  if(base+2<n) v2=in[base+2];
  if(base+3<n) v3=in[base+3];
  ts[t]=v0+v1+v2+v3; __syncthreads();
  for(int off=1; off<256; off<<=1){
    int x = (t>=off)? ts[t-off] : 0; __syncthreads();
    ts[t]+=x; __syncthreads();
  }
  int ex = (t==0)? 0 : ts[t-1];
  if(base+0<n) part[base+0]=ex;
  if(base+1<n) part[base+1]=ex+v0;
  if(base+2<n) part[base+2]=ex+v0+v1;
  if(base+3<n) part[base+3]=ex+v0+v1+v2;
  if(t==255) bsum[blockIdx.x]=ts[255];
}

__global__ void kscan2(int* __restrict__ b, int n){
  __shared__ int ts[256];
  int t = threadIdx.x;
  int v[16]; int s=0;
#pragma unroll
  for(int k=0;k<16;k++){ int p=t*16+k; v[k] = (p<n)? b[p] : 0; s+=v[k]; }
  ts[t]=s; __syncthreads();
  for(int off=1; off<256; off<<=1){
    int x = (t>=off)? ts[t-off] : 0; __syncthreads();
    ts[t]+=x; __syncthreads();
  }
  int run = (t==0)? 0 : ts[t-1];
#pragma unroll
  for(int k=0;k<16;k++){ int p=t*16+k; if(p<n) b[p]=run; run+=v[k]; }
}

__global__ void kscan3(const int* __restrict__ part, const int* __restrict__ bsum,
                       int* __restrict__ offs, int* __restrict__ cursor, int n){
  int i = blockIdx.x*blockDim.x + threadIdx.x;
  if(i==0) offs[n] = PT_TOT;
  if(i>=n) return;
  int v = part[i] + bsum[i>>10];
  offs[i]=v; cursor[i]=v;
}

__global__ void kpack(const float* __restrict__ hadx, const float* __restrict__ icx,
                      const float* __restrict__ igx,
                      const float* __restrict__ hady, const float* __restrict__ icy,
                      const float* __restrict__ igy,
                      int* __restrict__ cursor,
                      float* __restrict__ had_rec, float* __restrict__ ico_rec,
                      float* __restrict__ igra_rec){
  int idx = blockIdx.x*blockDim.x + threadIdx.x;
  if(idx >= PT_TOT) return;
  PtLoc p = ptloc(idx, hadx, icx, igx);
  int cell = vbglobal(p)*SP + binx(p.x)*GYN + biny(p.y);
  int pos = atomicAdd(cursor + cell, 1);
  if(p.ds==0){
    float* r = had_rec + (size_t)pos*4;
    r[0]=p.x; r[1]=p.y;
    r[2]=hady[(size_t)p.vb*5000 + p.n];
  } else if(p.ds==1){
    float* r = ico_rec + (size_t)(pos - P_HAD)*8;
    r[0]=p.x; r[1]=p.y;
#pragma unroll
    for(int c=0;c<5;c++) r[2+c]=icy[((size_t)p.vb*5 + c)*20000 + p.n];
  } else {
    float* r = igra_rec + (size_t)(pos - P_HAD - P_ICO)*28;
    r[0]=p.x; r[1]=p.y;
#pragma unroll
    for(int c=0;c<24;c++) r[2+c]=igy[((size_t)p.vb*24 + c)*3000 + p.n];
  }
}

// ====================== mega kernel helpers ================================
__device__ __forceinline__ void copy_one(int cc, int b, int i, int j,
    const float* __restrict__ iasi, const float* __restrict__ ascat,
    const float* __restrict__ elev, const float* __restrict__ clim,
    const float* __restrict__ aux, float* __restrict__ out){
  float v; int oc;
  if(cc < 8){
    int hi = i>>1, wi = ((120 - j)*60)/121;
    v = iasi[((b*120 + hi)*60 + wi)*8 + cc];
    if(!isfinite(v)) v = isnan(v) ? 0.f : (v>0.f? 3.4028235e38f : -3.4028235e38f);
    oc = cc;
  } else if(cc < 11){
    int hi = i>>1, wi = ((120 - j)*60)/121;
    v = ascat[((b*120 + hi)*60 + wi)*3 + (cc-8)];
    if(!isfinite(v)) v = isnan(v) ? 0.f : (v>0.f? 3.4028235e38f : -3.4028235e38f);
    oc = cc;
  } else if(cc == 11){
    v = elev[(b*480 + 2*i)*242 + (241 - 2*j)];
    oc = 183;
  } else if(cc < 36){
    int c = cc-12;
    v = clim[(((size_t)b*24 + c)*GXN + i)*GYN + j];
    oc = 184 + c;
  } else {
    v = aux[b*5 + (cc-36)];
    oc = 208 + (cc-36);
  }
  out[oidx(b,oc,i,j)] = v;
}

// generic on-grid setconv: up to 4 channels per thread, arbitrary strides
__device__ __forceinline__ void ongrid(const float* __restrict__ lon, const float* __restrict__ lat,
    const float* __restrict__ base, int H, int W, int sH, int sW, int sC,
    int c0, int cg, int maskedC, bool zmask, int chOut,
    float inv2, float dmax, int b, int i, int j, float* __restrict__ out){
  float gi = gxv(i), gj = gyv(j);
  int hlo = lbnd(lon,H,gi-dmax), hhi = ubnd(lon,H,gi+dmax);
  int wlo = lbnd(lat,W,gj-dmax), whi = ubnd(lat,W,gj+dmax);
  float den[4]={0.f,0.f,0.f,0.f}, sig[4]={0.f,0.f,0.f,0.f};
  for(int h=hlo; h<hhi; h++){
    float dx = lon[h]-gi;
    float ax = -dx*dx*inv2;
    if(ax < ACLIP) continue;
    const float* rowp = base + (size_t)h*sH + (size_t)c0*sC;
    for(int w=wlo; w<whi; w++){
      float dy = lat[w]-gj;
      float a = ax - dy*dy*inv2;
      if(a < ACLIP) continue;
      float wt = expf(a);
      const float* s = rowp + (size_t)w*sW;
#pragma unroll
      for(int c=0;c<4;c++){
        if(c<cg){
          float v = s[c*sC];
          bool ok = isfinite(v);
          if(zmask) ok = ok && (v!=0.0f);
          if(c0+c == maskedC) ok = false;
          if(ok){ den[c]+=wt; sig[c]+=wt*v; }
        }
      }
    }
  }
#pragma unroll
  for(int c=0;c<4;c++){
    if(c<cg){
      size_t d = oidx(b, chOut + 2*c, i, j);
      out[d]    = den[c];
      out[d+SP] = sig[c]/(den[c]+EPSV);
    }
  }
}

// generic off-grid gather from packed records
__device__ __forceinline__ void offgrid(const float* __restrict__ rec, int RS,
    const int* __restrict__ offs, int dsBase, int vbG, int voff, int cg, int chOut,
    float inv2, float dmax, int b, int i, int j, float* __restrict__ out){
  int rbx = (int)floorf(dmax*239.0f + 0.5f);
  int rby = (int)floorf(dmax*240.0f + 0.5f);
  float gi = gxv(i), gj = gyv(j);
  int ilo = i-rbx; if(ilo<0) ilo=0;
  int ihi = i+rbx; if(ihi>GXN-1) ihi=GXN-1;
  int jlo = j-rby; if(jlo<0) jlo=0;
  int jhi = j+rby; if(jhi>GYN-1) jhi=GYN-1;
  int jspan = jhi - jlo;
  float den[4]={0.f,0.f,0.f,0.f}, sig[4]={0.f,0.f,0.f,0.f};
  for(int bi=ilo; bi<=ihi; bi++){
    int cb0 = vbG*SP + bi*GYN + jlo;
    int s = offs[cb0] - dsBase;
    int e = offs[cb0 + jspan + 1] - dsBase;
    for(int t=s; t<e; t++){
      const float* r = rec + (size_t)t*RS;
      float dx = r[0]-gi, dy = r[1]-gj;
      float a = -(dx*dx + dy*dy)*inv2;
      if(a < ACLIP) continue;
      float wt = expf(a);
#pragma unroll
      for(int c=0;c<4;c++){
        if(c<cg){
          float v = r[voff+c];
          if(isfinite(v)){ den[c]+=wt; sig[c]+=wt*v; }
        }
      }
    }
  }
#pragma unroll
  for(int c=0;c<4;c++){
    if(c<cg){
      size_t d = oidx(b, chOut + 2*c, i, j);
      out[d]    = den[c];
      out[d+SP] = sig[c]/(den[c]+EPSV);
    }
  }
}

// ====================== the mega kernel ====================================
// groups: 0-10 copy(41ch), 11-12 GRIDSAT, 13-16 AMSU-A, 17-19 AMSU-B,
//         20-26 HIRS, 27-30 HadISD, 31-32 ICOADS, 33-38 IGRA
__global__ __launch_bounds__(256) void kmega(
    const float* __restrict__ iasi, const float* __restrict__ ascat,
    const float* __restrict__ elev, const float* __restrict__ clim,
    const float* __restrict__ aux,
    const float* __restrict__ slon, const float* __restrict__ slat, const float* __restrict__ scur,
    const float* __restrict__ alon, const float* __restrict__ alat, const float* __restrict__ acur,
    const float* __restrict__ blon, const float* __restrict__ blat, const float* __restrict__ bcur,
    const float* __restrict__ hlon, const float* __restrict__ hlat, const float* __restrict__ hcur,
    const float* __restrict__ had_rec, const float* __restrict__ ico_rec,
    const float* __restrict__ igra_rec, const int* __restrict__ offs,
    const float* __restrict__ lsp, float* __restrict__ out){
  int g = blockIdx.x / CBLK;
  int t = (blockIdx.x % CBLK)*blockDim.x + threadIdx.x;
  if(t >= NB*SP) return;
  int j = t%GYN; int i = (t/GYN)%GXN; int b = t/SP;
  float ls = lsp[0];
  float inv2 = 0.5f/(ls*ls);
  float dmax = DMAXF*ls;

  if(g < 11){
    int cb = g*4;
#pragma unroll
    for(int k=0;k<4;k++){
      int cc = cb+k;
      if(cc < 41) copy_one(cc, b, i, j, iasi, ascat, elev, clim, aux, out);
    }
  } else if(g < 13){
    int c0 = g-11;  // GRIDSAT: (B,C=2,H=360,W=180), ch 29
    ongrid(slon + b*360, slat + b*180, scur + (size_t)b*2*360*180,
           360, 180, 180, 1, 64800, c0, 1, -1, false, 29 + 2*c0,
           inv2, dmax, b, i, j, out);
  } else if(g < 17){
    int c0 = (g-13)*4;  // AMSU-A: acur (B,121,240,13) -> strides H:13 W:3120 C:1, ch 33
    int cg = 13-c0 < 4 ? 13-c0 : 4;
    ongrid(alon + b*240, alat + b*121, acur + (size_t)b*121*240*13,
           240, 121, 13, 3120, 1, c0, cg, 12, true, 33 + 2*c0,
           inv2, dmax, b, i, j, out);
  } else if(g < 20){
    int c0 = (g-17)*4;  // AMSU-B: bcur (B,240,121,12) -> strides H:1452 W:12 C:1, ch 59
    ongrid(blon + b*240, blat + b*121, bcur + (size_t)b*240*121*12,
           240, 121, 1452, 12, 1, c0, 4, -1, true, 59 + 2*c0,
           inv2, dmax, b, i, j, out);
  } else if(g < 27){
    int c0 = (g-20)*4;  // HIRS: hcur (B,240,121,26) -> strides H:3146 W:26 C:1, ch 131
    int cg = 26-c0 < 4 ? 26-c0 : 4;
    ongrid(hlon + b*240, hlat + b*121, hcur + (size_t)b*240*121*26,
           240, 121, 3146, 26, 1, c0, cg, -1, true, 131 + 2*c0,
           inv2, dmax, b, i, j, out);
  } else if(g < 31){
    int set = g-27;     // HadISD: C=1, vbG = set*8+b, ch 11+2*set
    offgrid(had_rec, 4, offs, 0, set*8 + b, 2, 1, 11 + 2*set,
            inv2, dmax, b, i, j, out);
  } else if(g < 33){
    int c0 = (g-31)*4;  // ICOADS: C=5, vbG = 32+b, ch 19
    int cg = 5-c0 < 4 ? 5-c0 : 4;
    offgrid(ico_rec, 8, offs, P_HAD, 32 + b, 2 + c0, cg, 19 + 2*c0,
            inv2, dmax, b, i, j, out);
  } else {
    int c0 = (g-33)*4;  // IGRA: C=24, vbG = 40+b, ch 83
    offgrid(igra_rec, 28, offs, P_HAD + P_ICO, 40 + b, 2 + c0, 4, 83 + 2*c0,
            inv2, dmax, b, i, j, out);
  }
}

extern "C" void kernel_launch(void* const* d_in, const int* in_sizes, int n_in,
                              void* d_out, int out_size, void* d_ws, size_t ws_size,
                              hipStream_t stream){
  const float* iasi  = (const float*)d_in[0];
  const float* ascat = (const float*)d_in[1];
  const float* hadx  = (const float*)d_in[2];   // (4,8,2,5000)
  const float* hady  = (const float*)d_in[3];   // (4,8,5000)
  const float* icx   = (const float*)d_in[4];   // (8,2,20000)
  const float* icy   = (const float*)d_in[5];   // (8,5,20000)
  const float* slon  = (const float*)d_in[6];
  const float* slat  = (const float*)d_in[7];
  const float* scur  = (const float*)d_in[8];   // (8,2,360,180)
  const float* alon  = (const float*)d_in[9];
  const float* alat  = (const float*)d_in[10];
  const float* acur  = (const float*)d_in[11];  // (8,121,240,13)
  const float* blon  = (const float*)d_in[12];
  const float* blat  = (const float*)d_in[13];
  const float* bcur  = (const float*)d_in[14];  // (8,240,121,12)
  const float* hlon  = (const float*)d_in[15];
  const float* hlat  = (const float*)d_in[16];
  const float* hcur  = (const float*)d_in[17];  // (8,240,121,26)
  const float* igx   = (const float*)d_in[18];  // (8,2,3000)
  const float* igy   = (const float*)d_in[19];  // (8,24,3000)
  const float* elev  = (const float*)d_in[20];  // (8,1,480,242)
  const float* clim  = (const float*)d_in[21];  // (8,24,240,121)
  const float* aux   = (const float*)d_in[22];  // (8,5)
  const float* ls    = (const float*)d_in[23];
  float* out = (float*)d_out;
  dim3 tb(256);
  auto nb = [](long long n){ return dim3((unsigned)((n+255)/256)); };

  // workspace layout (~21.6 MB)
  int* counts = (int*)d_ws;                 // NCELL (doubles as cursor)
  int* offs   = counts + NCELL;             // NCELL+1
  int* bsum   = offs + NCELL + 1;           // 4096
  float* had_rec  = (float*)(bsum + 4096);  // 160000*4
  float* ico_rec  = had_rec + 640000;       // 160000*8
  float* igra_rec = ico_rec + 1280000;      // 24000*28

  int nblk = (NCELL + 1023)/1024;           // 1362

  kzero_i<<<nb(NCELL),tb,0,stream>>>(counts, NCELL);
  kcount <<<nb(PT_TOT),tb,0,stream>>>(hadx, icx, igx, counts);
  kscan1 <<<dim3(nblk),tb,0,stream>>>(counts, offs, bsum, NCELL);
  kscan2 <<<dim3(1),tb,0,stream>>>(bsum, nblk);
  kscan3 <<<nb(NCELL),tb,0,stream>>>(offs, bsum, offs, counts, NCELL);
  kpack  <<<nb(PT_TOT),tb,0,stream>>>(hadx, icx, igx, hady, icy, igy,
                                      counts, had_rec, ico_rec, igra_rec);

  kmega<<<dim3(NGROUP*CBLK),tb,0,stream>>>(iasi, ascat, elev, clim, aux,
      slon, slat, scur, alon, alat, acur, blon, blat, bcur, hlon, hlat, hcur,
      had_rec, ico_rec, igra_rec, offs, ls, out);
}

// Round 5
// 694.646 us; speedup vs baseline: 1.1591x; 1.1591x over previous
//
#include <hip/hip_runtime.h>
#include <cmath>

#define GXN 240
#define GYN 121
#define SP  29040   // GXN*GYN
#define NB  8
#define NCH 213
#define EPSV 1e-6f
#define DMAXF 7.75f   // sqrt(2*30) * ls  -> weight >= ~9.4e-14 kept
#define ACLIP -30.0f

// unified off-grid point space: HadISD(32 vb x 5000) + ICOADS(8 x 20000) + IGRA(8 x 3000)
#define P_HAD   160000
#define P_ICO   160000
#define P_IGRA  24000
#define PT_TOT  344000
#define VB_TOT  48
#define NCELL   (VB_TOT*SP)   // 1,393,920
#define CBLK    908           // ceil(NB*SP/256)
#define NGOFF   23            // groups in kmoff

__device__ __forceinline__ float gxv(int i){ return (float)i * (1.0f/239.0f); }
__device__ __forceinline__ float gyv(int j){ return -0.25f + (float)j * (1.0f/240.0f); }
__device__ __forceinline__ size_t oidx(int b,int c,int i,int j){
  return (((size_t)b*NCH + c)*GXN + i)*GYN + j;
}
__device__ __forceinline__ int binx(float x){
  int i = (int)floorf(x*239.0f + 0.5f);
  return i<0?0:(i>239?239:i);
}
__device__ __forceinline__ int biny(float y){
  int j = (int)floorf((y+0.25f)*240.0f + 0.5f);
  return j<0?0:(j>120?120:j);
}
__device__ __forceinline__ int lbnd(const float* a, int n, float v){
  int lo=0, hi=n;
  while(lo<hi){ int m=(lo+hi)>>1; if(a[m]<v) lo=m+1; else hi=m; }
  return lo;
}
__device__ __forceinline__ int ubnd(const float* a, int n, float v){
  int lo=0, hi=n;
  while(lo<hi){ int m=(lo+hi)>>1; if(a[m]<=v) lo=m+1; else hi=m; }
  return lo;
}

// map unified point idx -> (dataset, vb, n, x, y)
struct PtLoc { int ds, vb, n; float x, y; };
__device__ __forceinline__ PtLoc ptloc(int idx, const float* hadx, const float* icx, const float* igx){
  PtLoc p;
  if(idx < P_HAD){
    p.ds=0; p.vb=idx/5000; p.n=idx%5000;
    p.x = hadx[(size_t)p.vb*10000 + p.n];
    p.y = hadx[(size_t)p.vb*10000 + 5000 + p.n];
  } else if(idx < P_HAD + P_ICO){
    int t = idx - P_HAD; p.ds=1; p.vb=t/20000; p.n=t%20000;
    p.x = icx[(size_t)p.vb*40000 + p.n];
    p.y = icx[(size_t)p.vb*40000 + 20000 + p.n];
  } else {
    int t = idx - (P_HAD+P_ICO); p.ds=2; p.vb=t/3000; p.n=t%3000;
    p.x = igx[(size_t)p.vb*6000 + p.n];
    p.y = igx[(size_t)p.vb*6000 + 3000 + p.n];
  }
  return p;
}
__device__ __forceinline__ int vbglobal(const PtLoc& p){
  return (p.ds==0)? p.vb : (p.ds==1? 32+p.vb : 40+p.vb);
}

// ====================== binning pipeline ====================================
__global__ void kzero_i(int* __restrict__ p, int n){
  int i = blockIdx.x*blockDim.x + threadIdx.x;
  if(i<n) p[i]=0;
}

__global__ void kcount(const float* __restrict__ hadx, const float* __restrict__ icx,
                       const float* __restrict__ igx, int* __restrict__ counts){
  int idx = blockIdx.x*blockDim.x + threadIdx.x;
  if(idx >= PT_TOT) return;
  PtLoc p = ptloc(idx, hadx, icx, igx);
  atomicAdd(counts + vbglobal(p)*SP + binx(p.x)*GYN + biny(p.y), 1);
}

__global__ void kscan1(const int* __restrict__ in, int* __restrict__ part,
                       int* __restrict__ bsum, int n){
  __shared__ int ts[256];
  int t = threadIdx.x;
  int base = blockIdx.x*1024 + t*4;
  int v0=0,v1=0,v2=0,v3=0;
  if(base+0<n) v0=in[base+0];
  if(base+1<n) v1=in[base+1];
  if(base+2<n) v2=in[base+2];
  if(base+3<n) v3=in[base+3];
  ts[t]=v0+v1+v2+v3; __syncthreads();
  for(int off=1; off<256; off<<=1){
    int x = (t>=off)? ts[t-off] : 0; __syncthreads();
    ts[t]+=x; __syncthreads();
  }
  int ex = (t==0)? 0 : ts[t-1];
  if(base+0<n) part[base+0]=ex;
  if(base+1<n) part[base+1]=ex+v0;
  if(base+2<n) part[base+2]=ex+v0+v1;
  if(base+3<n) part[base+3]=ex+v0+v1+v2;
  if(t==255) bsum[blockIdx.x]=ts[255];
}

__global__ void kscan2(int* __restrict__ b, int n){
  __shared__ int ts[256];
  int t = threadIdx.x;
  int v[16]; int s=0;
#pragma unroll
  for(int k=0;k<16;k++){ int p=t*16+k; v[k] = (p<n)? b[p] : 0; s+=v[k]; }
  ts[t]=s; __syncthreads();
  for(int off=1; off<256; off<<=1){
    int x = (t>=off)? ts[t-off] : 0; __syncthreads();
    ts[t]+=x; __syncthreads();
  }
  int run = (t==0)? 0 : ts[t-1];
#pragma unroll
  for(int k=0;k<16;k++){ int p=t*16+k; if(p<n) b[p]=run; run+=v[k]; }
}

__global__ void kscan3(const int* __restrict__ part, const int* __restrict__ bsum,
                       int* __restrict__ offs, int* __restrict__ cursor, int n){
  int i = blockIdx.x*blockDim.x + threadIdx.x;
  if(i==0) offs[n] = PT_TOT;
  if(i>=n) return;
  int v = part[i] + bsum[i>>10];
  offs[i]=v; cursor[i]=v;
}

// pack records per channel-GROUP: each group gets compact (x,y,v0..v3) streams
__global__ void kpack(const float* __restrict__ hadx, const float* __restrict__ icx,
                      const float* __restrict__ igx,
                      const float* __restrict__ hady, const float* __restrict__ icy,
                      const float* __restrict__ igy,
                      int* __restrict__ cursor,
                      float* __restrict__ had_rec, float* __restrict__ ico_rec,
                      float* __restrict__ igra_rec){
  int idx = blockIdx.x*blockDim.x + threadIdx.x;
  if(idx >= PT_TOT) return;
  PtLoc p = ptloc(idx, hadx, icx, igx);
  int cell = vbglobal(p)*SP + binx(p.x)*GYN + biny(p.y);
  int pos = atomicAdd(cursor + cell, 1);
  if(p.ds==0){
    float* r = had_rec + (size_t)pos*4;
    r[0]=p.x; r[1]=p.y;
    r[2]=hady[(size_t)p.vb*5000 + p.n];
  } else if(p.ds==1){
    int lp = pos - P_HAD;
    float* r0 = ico_rec + (size_t)lp*6;
    r0[0]=p.x; r0[1]=p.y;
#pragma unroll
    for(int c=0;c<4;c++) r0[2+c]=icy[((size_t)p.vb*5 + c)*20000 + p.n];
    float* r1 = ico_rec + 960000 + (size_t)lp*6;
    r1[0]=p.x; r1[1]=p.y;
    r1[2]=icy[((size_t)p.vb*5 + 4)*20000 + p.n];
  } else {
    int lp = pos - P_HAD - P_ICO;
#pragma unroll
    for(int g=0; g<6; g++){
      float* r = igra_rec + (size_t)g*144000 + (size_t)lp*6;
      r[0]=p.x; r[1]=p.y;
#pragma unroll
      for(int k=0;k<4;k++) r[2+k]=igy[((size_t)p.vb*24 + g*4 + k)*3000 + p.n];
    }
  }
}

// ---------------- AMSU-A transpose: (B,121,240,13) -> [b][h=240][w=121][13] --
__global__ void ktransA(const float* __restrict__ acur, float* __restrict__ planeA){
  int idx = blockIdx.x*blockDim.x + threadIdx.x;
  if(idx >= NB*121*240*13) return;
  int c = idx%13; int h=(idx/13)%240; int w=(idx/3120)%121; int b=idx/377520;
  planeA[(((size_t)b*240 + h)*121 + w)*13 + c] = acur[idx];
}

// ====================== on-grid row kernel ==================================
// block = one (dataset, b, i) output row; LDS-staged source rows; threads = j
template<int C, bool CHLAST>
__device__ __forceinline__ void ongrid_row(
    const float* __restrict__ lon, int H,
    const float* __restrict__ lat, int W,
    const float* __restrict__ src, size_t sH, size_t sW, size_t sC,
    int maskedC, bool zmask, int chOut,
    float inv2, float dmax, int b, int i,
    float* __restrict__ out, float* __restrict__ lds)
{
  float gi = gxv(i);
  int hlo = lbnd(lon,H,gi-dmax), hhi = ubnd(lon,H,gi+dmax);
  int j = threadIdx.x;
  bool act = j < GYN;
  float gj = gyv(act? j : 0);
  int wlo=0, whi=0;
  if(act){ wlo = lbnd(lat,W,gj-dmax); whi = ubnd(lat,W,gj+dmax); }
  float den[C], sig[C];
#pragma unroll
  for(int c=0;c<C;c++){ den[c]=0.f; sig[c]=0.f; }
  for(int h=hlo; h<hhi; h++){
    __syncthreads();
    const float* rp = src + (size_t)h*sH;
    if(CHLAST){
      for(int t=threadIdx.x; t<W*C; t+=blockDim.x) lds[t] = rp[t];
    } else {
      for(int t=threadIdx.x; t<W*C; t+=blockDim.x){
        int w=t/C, c=t%C;
        lds[t] = rp[(size_t)w*sW + (size_t)c*sC];
      }
    }
    __syncthreads();
    if(!act) continue;
    float dx = lon[h]-gi;
    float ax = -dx*dx*inv2;
    if(ax < ACLIP) continue;
    for(int w=wlo; w<whi; w++){
      float dy = lat[w]-gj;
      float a = ax - dy*dy*inv2;
      if(a < ACLIP) continue;
      float wt = expf(a);
      const float* s = lds + w*C;
#pragma unroll
      for(int c=0;c<C;c++){
        float v = s[c];
        bool ok = isfinite(v);
        if(zmask) ok = ok && (v!=0.0f);
        if(c==maskedC) ok = false;
        if(ok){ den[c]+=wt; sig[c]+=wt*v; }
      }
    }
  }
  if(act){
#pragma unroll
    for(int c=0;c<C;c++){
      size_t d = oidx(b, chOut+2*c, i, j);
      out[d]    = den[c];
      out[d+SP] = sig[c]/(den[c]+EPSV);
    }
  }
}

// ds 0: GRIDSAT  ds 1: AMSU-A(planeA)  ds 2: AMSU-B  ds 3: HIRS
__global__ __launch_bounds__(128) void kongrid(
    const float* __restrict__ slon, const float* __restrict__ slat, const float* __restrict__ scur,
    const float* __restrict__ alon, const float* __restrict__ alat, const float* __restrict__ planeA,
    const float* __restrict__ blon, const float* __restrict__ blat, const float* __restrict__ bcur,
    const float* __restrict__ hlon, const float* __restrict__ hlat, const float* __restrict__ hcur,
    const float* __restrict__ lsp, float* __restrict__ out)
{
  __shared__ float lds[3146];   // max row: HIRS 121*26
  int blk = blockIdx.x;
  int ds = blk / 1920, r = blk % 1920;
  int b = r/240, i = r%240;
  float ls = lsp[0];
  float inv2 = 0.5f/(ls*ls);
  float dmax = DMAXF*ls;
  if(ds==0){
    ongrid_row<2,false>(slon+b*360,360, slat+b*180,180,
      scur + (size_t)b*129600, 180,1,64800, -1,false, 29, inv2,dmax,b,i,out,lds);
  } else if(ds==1){
    ongrid_row<13,true>(alon+b*240,240, alat+b*121,121,
      planeA + (size_t)b*377520, 1573,13,1, 12,true, 33, inv2,dmax,b,i,out,lds);
  } else if(ds==2){
    ongrid_row<12,true>(blon+b*240,240, blat+b*121,121,
      bcur + (size_t)b*348480, 1452,12,1, -1,true, 59, inv2,dmax,b,i,out,lds);
  } else {
    ongrid_row<26,true>(hlon+b*240,240, hlat+b*121,121,
      hcur + (size_t)b*755040, 3146,26,1, -1,true, 131, inv2,dmax,b,i,out,lds);
  }
}

// ====================== off-grid + copies mega ==============================
__device__ __forceinline__ void copy_one(int cc, int b, int i, int j,
    const float* __restrict__ iasi, const float* __restrict__ ascat,
    const float* __restrict__ elev, const float* __restrict__ clim,
    const float* __restrict__ aux, float* __restrict__ out){
  float v; int oc;
  if(cc < 8){
    int hi = i>>1, wi = ((120 - j)*60)/121;
    v = iasi[((b*120 + hi)*60 + wi)*8 + cc];
    if(!isfinite(v)) v = isnan(v) ? 0.f : (v>0.f? 3.4028235e38f : -3.4028235e38f);
    oc = cc;
  } else if(cc < 11){
    int hi = i>>1, wi = ((120 - j)*60)/121;
    v = ascat[((b*120 + hi)*60 + wi)*3 + (cc-8)];
    if(!isfinite(v)) v = isnan(v) ? 0.f : (v>0.f? 3.4028235e38f : -3.4028235e38f);
    oc = cc;
  } else if(cc == 11){
    v = elev[(b*480 + 2*i)*242 + (241 - 2*j)];
    oc = 183;
  } else if(cc < 36){
    int c = cc-12;
    v = clim[(((size_t)b*24 + c)*GXN + i)*GYN + j];
    oc = 184 + c;
  } else {
    v = aux[b*5 + (cc-36)];
    oc = 208 + (cc-36);
  }
  out[oidx(b,oc,i,j)] = v;
}

__device__ __forceinline__ void offgrid(const float* __restrict__ rec, int RS,
    const int* __restrict__ offs, int dsBase, int vbG, int cg, int chOut,
    float inv2, float dmax, int b, int i, int j, float* __restrict__ out){
  int rbx = (int)floorf(dmax*239.0f + 0.5f);
  int rby = (int)floorf(dmax*240.0f + 0.5f);
  float gi = gxv(i), gj = gyv(j);
  int ilo = i-rbx; if(ilo<0) ilo=0;
  int ihi = i+rbx; if(ihi>GXN-1) ihi=GXN-1;
  int jlo = j-rby; if(jlo<0) jlo=0;
  int jhi = j+rby; if(jhi>GYN-1) jhi=GYN-1;
  int jspan = jhi - jlo;
  float den[4]={0.f,0.f,0.f,0.f}, sig[4]={0.f,0.f,0.f,0.f};
  for(int bi=ilo; bi<=ihi; bi++){
    int cb0 = vbG*SP + bi*GYN + jlo;
    int s = offs[cb0] - dsBase;
    int e = offs[cb0 + jspan + 1] - dsBase;
    for(int t=s; t<e; t++){
      const float* r = rec + (size_t)t*RS;
      float dx = r[0]-gi, dy = r[1]-gj;
      float a = -(dx*dx + dy*dy)*inv2;
      if(a < ACLIP) continue;
      float wt = expf(a);
#pragma unroll
      for(int c=0;c<4;c++){
        if(c<cg){
          float v = r[2+c];
          if(isfinite(v)){ den[c]+=wt; sig[c]+=wt*v; }
        }
      }
    }
  }
#pragma unroll
  for(int c=0;c<4;c++){
    if(c<cg){
      size_t d = oidx(b, chOut + 2*c, i, j);
      out[d]    = den[c];
      out[d+SP] = sig[c]/(den[c]+EPSV);
    }
  }
}

// groups: 0-10 copies(41ch), 11-14 HadISD, 15-16 ICOADS, 17-22 IGRA
__global__ __launch_bounds__(256) void kmoff(
    const float* __restrict__ iasi, const float* __restrict__ ascat,
    const float* __restrict__ elev, const float* __restrict__ clim,
    const float* __restrict__ aux,
    const float* __restrict__ had_rec, const float* __restrict__ ico_rec,
    const float* __restrict__ igra_rec, const int* __restrict__ offs,
    const float* __restrict__ lsp, float* __restrict__ out){
  int g = blockIdx.x / CBLK;
  int t = (blockIdx.x % CBLK)*blockDim.x + threadIdx.x;
  if(t >= NB*SP) return;
  int j = t%GYN; int i = (t/GYN)%GXN; int b = t/SP;
  float ls = lsp[0];
  float inv2 = 0.5f/(ls*ls);
  float dmax = DMAXF*ls;

  if(g < 11){
    int cb = g*4;
#pragma unroll
    for(int k=0;k<4;k++){
      int cc = cb+k;
      if(cc < 41) copy_one(cc, b, i, j, iasi, ascat, elev, clim, aux, out);
    }
  } else if(g < 15){
    int set = g-11;     // HadISD: C=1, vbG = set*8+b, ch 11+2*set
    offgrid(had_rec, 4, offs, 0, set*8 + b, 1, 11 + 2*set,
            inv2, dmax, b, i, j, out);
  } else if(g < 17){
    int grp = g-15;     // ICOADS: group 0 -> c0..3, group 1 -> c4
    offgrid(ico_rec + (size_t)grp*960000, 6, offs, P_HAD, 32 + b,
            grp==0?4:1, 19 + 8*grp, inv2, dmax, b, i, j, out);
  } else {
    int grp = g-17;     // IGRA: 6 groups of 4
    offgrid(igra_rec + (size_t)grp*144000, 6, offs, P_HAD + P_ICO, 40 + b,
            4, 83 + 8*grp, inv2, dmax, b, i, j, out);
  }
}

extern "C" void kernel_launch(void* const* d_in, const int* in_sizes, int n_in,
                              void* d_out, int out_size, void* d_ws, size_t ws_size,
                              hipStream_t stream){
  const float* iasi  = (const float*)d_in[0];
  const float* ascat = (const float*)d_in[1];
  const float* hadx  = (const float*)d_in[2];   // (4,8,2,5000)
  const float* hady  = (const float*)d_in[3];   // (4,8,5000)
  const float* icx   = (const float*)d_in[4];   // (8,2,20000)
  const float* icy   = (const float*)d_in[5];   // (8,5,20000)
  const float* slon  = (const float*)d_in[6];
  const float* slat  = (const float*)d_in[7];
  const float* scur  = (const float*)d_in[8];   // (8,2,360,180)
  const float* alon  = (const float*)d_in[9];
  const float* alat  = (const float*)d_in[10];
  const float* acur  = (const float*)d_in[11];  // (8,121,240,13)
  const float* blon  = (const float*)d_in[12];
  const float* blat  = (const float*)d_in[13];
  const float* bcur  = (const float*)d_in[14];  // (8,240,121,12)
  const float* hlon  = (const float*)d_in[15];
  const float* hlat  = (const float*)d_in[16];
  const float* hcur  = (const float*)d_in[17];  // (8,240,121,26)
  const float* igx   = (const float*)d_in[18];  // (8,2,3000)
  const float* igy   = (const float*)d_in[19];  // (8,24,3000)
  const float* elev  = (const float*)d_in[20];  // (8,1,480,242)
  const float* clim  = (const float*)d_in[21];  // (8,24,240,121)
  const float* aux   = (const float*)d_in[22];  // (8,5)
  const float* ls    = (const float*)d_in[23];
  float* out = (float*)d_out;
  dim3 tb(256);
  auto nb = [](long long n){ return dim3((unsigned)((n+255)/256)); };

  // workspace layout (~37 MB)
  int* counts = (int*)d_ws;                 // NCELL (doubles as cursor)
  int* offs   = counts + NCELL;             // NCELL+1
  int* bsum   = offs + NCELL + 1;           // 4096
  float* had_rec  = (float*)(bsum + 4096);  // 160000*4
  float* ico_rec  = had_rec + 640000;       // 2*160000*6
  float* igra_rec = ico_rec + 1920000;      // 6*24000*6
  float* planeA   = igra_rec + 864000;      // 8*240*121*13

  int nblk = (NCELL + 1023)/1024;           // 1362

  // AMSU-A source transpose (independent of binning)
  ktransA<<<nb((long long)NB*121*240*13),tb,0,stream>>>(acur, planeA);

  // off-grid binning
  kzero_i<<<nb(NCELL),tb,0,stream>>>(counts, NCELL);
  kcount <<<nb(PT_TOT),tb,0,stream>>>(hadx, icx, igx, counts);
  kscan1 <<<dim3(nblk),tb,0,stream>>>(counts, offs, bsum, NCELL);
  kscan2 <<<dim3(1),tb,0,stream>>>(bsum, nblk);
  kscan3 <<<nb(NCELL),tb,0,stream>>>(offs, bsum, offs, counts, NCELL);
  kpack  <<<nb(PT_TOT),tb,0,stream>>>(hadx, icx, igx, hady, icy, igy,
                                      counts, had_rec, ico_rec, igra_rec);

  // on-grid setconvs: 4 datasets x 1920 row-blocks
  kongrid<<<dim3(4*1920),dim3(128),0,stream>>>(slon, slat, scur,
      alon, alat, planeA, blon, blat, bcur, hlon, hlat, hcur, ls, out);

  // copies + off-grid gathers
  kmoff<<<dim3(NGOFF*CBLK),tb,0,stream>>>(iasi, ascat, elev, clim, aux,
      had_rec, ico_rec, igra_rec, offs, ls, out);
}